// Round 13
// baseline (630.868 us; speedup 1.0000x reference)
//
#include <hip/hip_runtime.h>
#include <stdint.h>

typedef unsigned short u16;
typedef unsigned long long u64;
typedef __bf16 bf16x8 __attribute__((ext_vector_type(8)));
typedef float f32x4 __attribute__((ext_vector_type(4)));
typedef float f32x16 __attribute__((ext_vector_type(16)));

#define NB 4
#define NS 2048
#define NC 256
#define NH 8
#define NM (NB*NS)        // 8192 rows (b,s)
#define NQKV (3*NH*NC)    // 6144
#define NHC (NH*NC)       // 2048

__device__ __forceinline__ u16 f2b(float f) {
  uint32_t u = __builtin_bit_cast(uint32_t, f);
  u += 0x7FFFu + ((u >> 16) & 1u);   // RNE
  return (u16)(u >> 16);
}
__device__ __forceinline__ void gl_lds16(const void* g, void* s) {
  __builtin_amdgcn_global_load_lds((const __attribute__((address_space(1))) void*)g,
                                   (__attribute__((address_space(3))) void*)s, 16, 0, 0);
}
// v_permlane32_swap_b32: a' = {lanes<32: a, lanes>=32: b[l-32]};
//                        b' = {lanes<32: a[l+32], lanes>=32: b}
__device__ __forceinline__ void pl32swap(uint32_t& a, uint32_t& b) {
  typedef int v2i __attribute__((ext_vector_type(2)));
  v2i r = __builtin_amdgcn_permlane32_swap((int)a, (int)b, false, false);
  a = (uint32_t)r.x; b = (uint32_t)r.y;
}
__device__ __forceinline__ uint32_t cvtpk(float lo, float hi) {
  uint32_t d;
  asm("v_cvt_pk_bf16_f32 %0, %1, %2" : "=v"(d) : "v"(lo), "v"(hi));
  return d;
}

// ---------------- prep: f32 -> bf16, weight transposes ----------------------
__global__ void prep_kernel(const float* __restrict__ x, const float* __restrict__ Wq,
                            const float* __restrict__ Wk, const float* __restrict__ Wv,
                            const float* __restrict__ Wfc,
                            u16* __restrict__ xb, u16* __restrict__ wt, u16* __restrict__ wfct) {
  const int total = NM*NC + NQKV*NC + NC*NHC;
  for (int i = blockIdx.x*blockDim.x + threadIdx.x; i < total; i += gridDim.x*blockDim.x) {
    if (i < NM*NC) {
      xb[i] = f2b(x[i]);
    } else if (i < NM*NC + NQKV*NC) {
      int j = i - NM*NC;              // j = n*256 + c ; n = proj*2048 + h*256 + d
      int n = j >> 8, c = j & 255;
      int proj = n >> 11, h = (n >> 8) & 7, d = n & 255;
      const float* W = (proj == 0) ? Wq : (proj == 1) ? Wk : Wv;
      wt[j] = f2b(W[((size_t)(h*NC + c))*NC + d]);     // wt[n][c] = W[h][c][d]
    } else {
      int j = i - NM*NC - NQKV*NC;    // j = d*2048 + jj
      int d = j >> 11, jj = j & 2047;
      wfct[j] = f2b(Wfc[(size_t)jj*NC + d]);           // wfct[d][jj] = Wfc[jj][d]
    }
  }
}

// ---------------- fused QKV projection GEMM (head-group aware) --------------
// Q/K scatter row-major to [b,hloc,s,d]; V scatters TILED-TRANSPOSED to
// [b,hloc][kt=s>>5][256 d][32 s&31]  (16KB contiguous per attn KV-tile).
__global__ void gemm_qkv(const u16* __restrict__ xb, const u16* __restrict__ wt,
                         const float* __restrict__ bq, const float* __restrict__ bk,
                         const float* __restrict__ bv,
                         u16* __restrict__ qo, u16* __restrict__ ko, u16* __restrict__ vo,
                         int h0, int hg, int lg_hg) {
  __shared__ u16 As[128*32];
  __shared__ u16 Bs[128*32];
  const int tid = threadIdx.x;
  const int w = tid >> 6, l = tid & 63;
  const int wr = w >> 1, wc = w & 1;
  const int m0 = blockIdx.x * 128;
  const int n0 = blockIdx.y * 128;             // within group N
  const int proj = n0 >> (8 + lg_hg);          // n0 / (hg*256)
  const int rem  = n0 & ((hg << 8) - 1);
  const int hloc = rem >> 8;
  const int dbase = rem & 255;                 // 0 or 128
  const int wrow0 = proj*2048 + ((h0 + hloc) << 8) + dbase;
  const int arow = tid >> 2;          // 0..63
  const int acol = (tid & 3) * 8;     // elems
  f32x4 acc[4][4] = {};
  for (int k0 = 0; k0 < 256; k0 += 32) {
    __syncthreads();
#pragma unroll
    for (int i = 0; i < 2; i++) {
      gl_lds16(xb + (size_t)(m0 + i*64 + arow)*256 + k0 + acol, (char*)As + i*4096 + w*1024);
      gl_lds16(wt + (size_t)(wrow0 + i*64 + arow)*256 + k0 + acol, (char*)Bs + i*4096 + w*1024);
    }
    __syncthreads();
    bf16x8 af[4], bfr[4];
#pragma unroll
    for (int mt = 0; mt < 4; mt++)
      af[mt] = *(const bf16x8*)&As[(wr*64 + mt*16 + (l&15))*32 + (l>>4)*8];
#pragma unroll
    for (int nt = 0; nt < 4; nt++)
      bfr[nt] = *(const bf16x8*)&Bs[(wc*64 + nt*16 + (l&15))*32 + (l>>4)*8];
#pragma unroll
    for (int mt = 0; mt < 4; mt++)
#pragma unroll
      for (int nt = 0; nt < 4; nt++)
        acc[mt][nt] = __builtin_amdgcn_mfma_f32_16x16x32_bf16(af[mt], bfr[nt], acc[mt][nt], 0, 0, 0);
  }
  if (proj == 2) {
    // V: +bias, ->bf16, tiled-transposed store (8B packed; s base mult of 4)
#pragma unroll
    for (int mt = 0; mt < 4; mt++) {
#pragma unroll
      for (int nt = 0; nt < 4; nt++) {
        const int dd = dbase + wc*64 + nt*16 + (l & 15);
        const float bb_ = bv[((h0 + hloc) << 8) + dd];
        const int m = m0 + wr*64 + mt*16 + ((l>>4)<<2);
        const int b = m >> 11, s = m & 2047;
        u16 pk[4];
#pragma unroll
        for (int j = 0; j < 4; j++) pk[j] = f2b(acc[mt][nt][j] + bb_);
        *(u64*)&vo[(size_t)(b*hg + hloc)*524288 + (size_t)(s>>5)*8192 + dd*32 + (s&31)]
            = *(const u64*)pk;
      }
    }
  } else {
    const float* bias = (proj == 0) ? bq : bk;
    u16* dst = (proj == 0) ? qo : ko;
#pragma unroll
    for (int mt = 0; mt < 4; mt++) {
#pragma unroll
      for (int nt = 0; nt < 4; nt++) {
        const int dd = dbase + wc*64 + nt*16 + (l & 15);
        const float bb_ = bias[((h0 + hloc) << 8) + dd];
#pragma unroll
        for (int j = 0; j < 4; j++) {
          const int m = m0 + wr*64 + mt*16 + ((l>>4)<<2) + j;
          const int b = m >> 11, s = m & 2047;
          dst[((size_t)((b*hg + hloc)*2048 + s))*256 + dd] = f2b(acc[mt][nt][j] + bb_);
        }
      }
    }
  }
}

// ---------------- flash attention: 32x32 MFMA, swapped operands -------------
// Wave = 32 q-rows, block = 128 q. KVBLK=32.
// K never touches LDS: the swapped A-frag K[kt*32+q31][ks*16+hh*8] is 16B
// contiguous in global, identical across waves, and the block's 16KB K-tile
// is L1-resident after first touch. K lives in registers, prefetched for
// kt+1 right after QK^T(kt) (T14: in flight under softmax+PV+barrier).
// V stays LDS (double-buffered, gl_lds from pre-swizzled tiled-transposed
// global). Softmax in-lane + permlane32_swap; P via cvt_pk (no LDS).
__global__ void __launch_bounds__(256, 2)
attn_kernel(const u16* __restrict__ q, const u16* __restrict__ k,
            const u16* __restrict__ vt, u16* __restrict__ cat,
            int h0, int hg, int lg_hg) {
  __shared__ u16 Vts[2][256*32];
  const int tid = threadIdx.x;
  const int w = tid >> 6, l = tid & 63;
  const int q31 = l & 31, hh = l >> 5;
  const int bh = blockIdx.y;                   // b*hg + hloc
  const int b = bh >> lg_hg, hloc = bh & (hg - 1);
  const int q0 = blockIdx.x * 128;
  const u16* qp  = q  + (size_t)bh * NS * 256;
  const u16* kp  = k  + (size_t)bh * NS * 256;
  const u16* vtp = vt + (size_t)bh * 524288;

  // Q B-frags: lane supplies Q[q=q31][d = ks*16 + hh*8 + e]
  bf16x8 qf[16];
  {
    const u16* qr = qp + (size_t)(q0 + w*32 + q31)*256 + hh*8;
#pragma unroll
    for (int ks = 0; ks < 16; ks++) qf[ks] = *(const bf16x8*)(qr + ks*16);
  }
  // K A-frags in registers; lane base walks rows kt*32+q31
  const u16* kgp = kp + (size_t)q31*256 + hh*8;
  bf16x8 kf[16];
#pragma unroll
  for (int ks = 0; ks < 16; ks++) kf[ks] = *(const bf16x8*)(kgp + ks*16);

  f32x16 o[8];
#pragma unroll
  for (int i = 0; i < 8; i++)
#pragma unroll
    for (int j = 0; j < 16; j++) o[i][j] = 0.f;
  float mrow = -1e30f, lsum = 0.f;
  const float sc = 0.0625f * 1.4426950408889634f;   // 1/sqrt(256) * log2(e)

  // stage V^T tile (16KB) into buffer buf
  auto stageV = [&](int buf, int kt) {
#pragma unroll
    for (int i = 0; i < 4; i++) {
      const int g = (w*4 + i)*64 + l;          // granule 0..1023
      const int vd = g >> 2, vcol = g & 3;
      gl_lds16(vtp + (size_t)kt*8192 + vd*32 + ((vcol ^ ((vd >> 1) & 3)) << 3),
               (char*)&Vts[buf][0] + (w*4 + i)*1024);
    }
  };

  stageV(0, 0);
  __syncthreads();

  for (int kt = 0; kt < NS/32; kt++) {
    const int buf = kt & 1;
    if (kt + 1 < NS/32) stageV(buf ^ 1, kt + 1);   // flies under compute

    // QK^T swapped: sacc = S^T[kv][q]: A = K (regs), B = Q (regs)
    f32x16 sacc;
#pragma unroll
    for (int i = 0; i < 16; i++) sacc[i] = 0.f;
    __builtin_amdgcn_s_setprio(1);
#pragma unroll
    for (int ks = 0; ks < 16; ks++)
      sacc = __builtin_amdgcn_mfma_f32_32x32x16_bf16(kf[ks], qf[ks], sacc, 0, 0, 0);
    __builtin_amdgcn_s_setprio(0);

    // prefetch K(kt+1) into kf — lands during softmax+PV+barrier.
    // (kt=63 reads 16KB past this bh's K: still inside d_ws; values unused.)
    {
      const u16* kn = kgp + (size_t)(kt + 1) * 8192;
#pragma unroll
      for (int ks = 0; ks < 16; ks++) kf[ks] = *(const bf16x8*)(kn + ks*16);
    }

    // softmax over kv (16 in-lane + partner via permlane32_swap), defer-max
    float m0 = fmaxf(fmaxf(sacc[0], sacc[1]),   fmaxf(sacc[2], sacc[3]));
    float m1 = fmaxf(fmaxf(sacc[4], sacc[5]),   fmaxf(sacc[6], sacc[7]));
    float m2 = fmaxf(fmaxf(sacc[8], sacc[9]),   fmaxf(sacc[10], sacc[11]));
    float m3 = fmaxf(fmaxf(sacc[12], sacc[13]), fmaxf(sacc[14], sacc[15]));
    float mo = fmaxf(fmaxf(m0, m1), fmaxf(m2, m3));
    uint32_t ma = __builtin_bit_cast(uint32_t, mo), mb = ma;
    pl32swap(ma, mb);
    const float pm = fmaxf(__builtin_bit_cast(float, ma),
                           __builtin_bit_cast(float, mb)) * sc;
    const bool upd = !__all(pm - mrow <= 8.0f);
    if (upd) {
      const float mn = fmaxf(mrow, pm);
      const float fr = exp2f(mrow - mn);
      mrow = mn; lsum *= fr;
#pragma unroll
      for (int i = 0; i < 8; i++) o[i] *= fr;
    }
    float p[16];
#pragma unroll
    for (int r = 0; r < 16; r++) p[r] = exp2f(sacc[r]*sc - mrow);
    float s0 = (p[0] + p[1]) + (p[2] + p[3]);
    float s1 = (p[4] + p[5]) + (p[6] + p[7]);
    float s2 = (p[8] + p[9]) + (p[10] + p[11]);
    float s3 = (p[12] + p[13]) + (p[14] + p[15]);
    float ps = (s0 + s1) + (s2 + s3);
    uint32_t sa = __builtin_bit_cast(uint32_t, ps), sb = sa;
    pl32swap(sa, sb);
    lsum += __builtin_bit_cast(float, sa) + __builtin_bit_cast(float, sb);

    // P -> bf16 B-frags entirely in registers (T12)
    uint32_t wv[8];
#pragma unroll
    for (int i = 0; i < 8; i++) wv[i] = cvtpk(p[2*i], p[2*i + 1]);
    pl32swap(wv[0], wv[2]); pl32swap(wv[1], wv[3]);
    pl32swap(wv[4], wv[6]); pl32swap(wv[5], wv[7]);
    uint4 u0; u0.x = wv[0]; u0.y = wv[1]; u0.z = wv[2]; u0.w = wv[3];
    uint4 u1; u1.x = wv[4]; u1.y = wv[5]; u1.z = wv[6]; u1.w = wv[7];
    const bf16x8 pb0 = __builtin_bit_cast(bf16x8, u0);
    const bf16x8 pb1 = __builtin_bit_cast(bf16x8, u1);

    // PV swapped: o[d][q] += mfma(V^T-frag, P-frag)
    __builtin_amdgcn_s_setprio(1);
#pragma unroll
    for (int dt = 0; dt < 8; dt++) {
      const int drow = dt*32 + q31;
      const int swz = (drow >> 1) & 3;
      const bf16x8 vf0 = *(const bf16x8*)&Vts[buf][drow*32 + ((hh ^ swz) << 3)];
      o[dt] = __builtin_amdgcn_mfma_f32_32x32x16_bf16(vf0, pb0, o[dt], 0, 0, 0);
      const bf16x8 vf1 = *(const bf16x8*)&Vts[buf][drow*32 + (((2 + hh) ^ swz) << 3)];
      o[dt] = __builtin_amdgcn_mfma_f32_32x32x16_bf16(vf1, pb1, o[dt], 0, 0, 0);
    }
    __builtin_amdgcn_s_setprio(0);

    __syncthreads();   // drains vmcnt (V stage + K prefetch landed)
  }

  // epilogue: o rows d = dt*32 + (r&3) + 8*(r>>2) + 4*hh, col q = q31
  const int hd = h0 + hloc;
  const float inv = 1.f / lsum;
  u16* crow = cat + ((size_t)(b*NS + (q0 + w*32 + q31))*8 + hd)*256 + 4*hh;
#pragma unroll
  for (int dt = 0; dt < 8; dt++) {
#pragma unroll
    for (int m = 0; m < 4; m++) {
      u16 pk4[4];
#pragma unroll
      for (int j = 0; j < 4; j++) pk4[j] = f2b(o[dt][4*m + j] * inv);
      *(u64*)&crow[dt*32 + 8*m] = *(const u64*)pk4;
    }
  }
}

// ---------------- FC GEMM + bias + residual (writes f32 to d_out) -----------
__global__ void gemm_fc(const u16* __restrict__ cat, const u16* __restrict__ wfct,
                        const float* __restrict__ bfc, const float* __restrict__ x,
                        float* __restrict__ fcb) {
  __shared__ u16 As[128*32];
  __shared__ u16 Bs[64*32];
  const int tid = threadIdx.x;
  const int w = tid >> 6, l = tid & 63;
  const int wr = w >> 1, wc = w & 1;
  const int m0 = blockIdx.x * 128;
  const int n0 = blockIdx.y * 64;
  const int arow = tid >> 2;
  const int acol = (tid & 3) * 8;
  f32x4 acc[4][2] = {};
  for (int k0 = 0; k0 < 2048; k0 += 32) {
    __syncthreads();
#pragma unroll
    for (int i = 0; i < 2; i++)
      gl_lds16(cat + (size_t)(m0 + i*64 + arow)*2048 + k0 + acol, (char*)As + i*4096 + w*1024);
    gl_lds16(wfct + (size_t)(n0 + arow)*2048 + k0 + acol, (char*)Bs + w*1024);
    __syncthreads();
    bf16x8 af[4], bfr[2];
#pragma unroll
    for (int mt = 0; mt < 4; mt++)
      af[mt] = *(const bf16x8*)&As[(wr*64 + mt*16 + (l&15))*32 + (l>>4)*8];
#pragma unroll
    for (int nt = 0; nt < 2; nt++)
      bfr[nt] = *(const bf16x8*)&Bs[(wc*32 + nt*16 + (l&15))*32 + (l>>4)*8];
#pragma unroll
    for (int mt = 0; mt < 4; mt++)
#pragma unroll
      for (int nt = 0; nt < 2; nt++)
        acc[mt][nt] = __builtin_amdgcn_mfma_f32_16x16x32_bf16(af[mt], bfr[nt], acc[mt][nt], 0, 0, 0);
  }
#pragma unroll
  for (int mt = 0; mt < 4; mt++) {
#pragma unroll
    for (int nt = 0; nt < 2; nt++) {
      const int n = n0 + wc*32 + nt*16 + (l & 15);
      const float bias = bfc[n];
#pragma unroll
      for (int j = 0; j < 4; j++) {
        const int m = m0 + wr*64 + mt*16 + ((l>>4)<<2) + j;
        fcb[(size_t)m*256 + n] = acc[mt][nt][j] + bias + x[(size_t)m*256 + n];
      }
    }
  }
}

// ---------------- LayerNorm (in-place on d_out) -----------------------------
__global__ void ln_kernel(const float* __restrict__ fcb, const float* __restrict__ gamma,
                          const float* __restrict__ beta, float* __restrict__ out) {
  const int row = blockIdx.x * 4 + (threadIdx.x >> 6);
  const int l = threadIdx.x & 63;
  const float* r = fcb + (size_t)row * 256;
  f32x4 vv = *(const f32x4*)(r + l*4);
  float s  = vv[0] + vv[1] + vv[2] + vv[3];
  float s2 = vv[0]*vv[0] + vv[1]*vv[1] + vv[2]*vv[2] + vv[3]*vv[3];
#pragma unroll
  for (int mof = 1; mof <= 32; mof <<= 1) {
    s  += __shfl_xor(s, mof);
    s2 += __shfl_xor(s2, mof);
  }
  const float mu = s * (1.f/256.f);
  const float var = s2 * (1.f/256.f) - mu*mu;
  const float rs = rsqrtf(var + 1e-5f);
  f32x4 ov;
#pragma unroll
  for (int j = 0; j < 4; j++)
    ov[j] = (vv[j] - mu) * rs * gamma[l*4 + j] + beta[l*4 + j];
  *(f32x4*)(out + (size_t)row*256 + l*4) = ov;
}

// ---------------- launch ----------------------------------------------------
extern "C" void kernel_launch(void* const* d_in, const int* in_sizes, int n_in,
                              void* d_out, int out_size, void* d_ws, size_t ws_size,
                              hipStream_t stream) {
  (void)in_sizes; (void)n_in; (void)out_size;
  const float* x     = (const float*)d_in[0];
  const float* Wq    = (const float*)d_in[1];
  const float* bq    = (const float*)d_in[2];
  const float* Wk    = (const float*)d_in[3];
  const float* bk    = (const float*)d_in[4];
  const float* Wv    = (const float*)d_in[5];
  const float* bv    = (const float*)d_in[6];
  const float* Wfc   = (const float*)d_in[7];
  const float* bfc   = (const float*)d_in[8];
  const float* gamma = (const float*)d_in[9];
  const float* beta  = (const float*)d_in[10];
  float* out = (float*)d_out;

  // Head-group size chosen from ws_size (deterministic). Footprint 40+12*hg MiB.
  int hg, lg_hg;
  if      (ws_size >= (136ull << 20)) { hg = 8; lg_hg = 3; }
  else if (ws_size >= (88ull  << 20)) { hg = 4; lg_hg = 2; }
  else if (ws_size >= (64ull  << 20)) { hg = 2; lg_hg = 1; }
  else                                { hg = 1; lg_hg = 0; }

  char* ws = (char*)d_ws;
  u16*   xb   = (u16*)(ws);                               //  4 MiB x bf16 [8192][256]
  u16*   wt   = (u16*)(ws + (4ull<<20));                  //  3 MiB Wqkv^T bf16 [6144][256]
  u16*   wfct = (u16*)(ws + (7ull<<20));                  //  1 MiB Wfc^T bf16 [256][2048]
  const size_t grp = (size_t)hg << 22;                    //  4*hg MiB per q/k/v buffer
  u16*   qb   = (u16*)(ws + (8ull<<20));
  u16*   kb   = (u16*)(ws + (8ull<<20) + grp);
  u16*   vb   = (u16*)(ws + (8ull<<20) + 2*grp);          // V tiled-transposed (32-tiles)
  u16*   catb = (u16*)(ws + (8ull<<20) + 3*grp);          // 32 MiB cat bf16 [8192][2048]

  prep_kernel<<<dim3(1024), dim3(256), 0, stream>>>(x, Wq, Wk, Wv, Wfc, xb, wt, wfct);
  for (int g = 0; g < NH / hg; g++) {
    const int h0 = g * hg;
    gemm_qkv<<<dim3(64, 6*hg), dim3(256), 0, stream>>>(xb, wt, bq, bk, bv, qb, kb, vb, h0, hg, lg_hg);
    attn_kernel<<<dim3(16, 4*hg), dim3(256), 0, stream>>>(qb, kb, vb, catb, h0, hg, lg_hg);
  }
  gemm_fc<<<dim3(64, 4), dim3(256), 0, stream>>>(catb, wfct, bfc, x, out);
  ln_kernel<<<dim3(2048), dim3(256), 0, stream>>>(out, gamma, beta, out);
}

// Round 14
// 298.126 us; speedup vs baseline: 2.1161x; 2.1161x over previous
//
#include <hip/hip_runtime.h>
#include <stdint.h>

typedef unsigned short u16;
typedef unsigned long long u64;
typedef __bf16 bf16x8 __attribute__((ext_vector_type(8)));
typedef float f32x4 __attribute__((ext_vector_type(4)));
typedef float f32x16 __attribute__((ext_vector_type(16)));

#define NB 4
#define NS 2048
#define NC 256
#define NH 8
#define NM (NB*NS)        // 8192 rows (b,s)
#define NQKV (3*NH*NC)    // 6144
#define NHC (NH*NC)       // 2048

__device__ __forceinline__ u16 f2b(float f) {
  uint32_t u = __builtin_bit_cast(uint32_t, f);
  u += 0x7FFFu + ((u >> 16) & 1u);   // RNE
  return (u16)(u >> 16);
}
__device__ __forceinline__ void gl_lds16(const void* g, void* s) {
  __builtin_amdgcn_global_load_lds((const __attribute__((address_space(1))) void*)g,
                                   (__attribute__((address_space(3))) void*)s, 16, 0, 0);
}
// v_permlane32_swap_b32: a' = {lanes<32: a, lanes>=32: b[l-32]};
//                        b' = {lanes<32: a[l+32], lanes>=32: b}
__device__ __forceinline__ void pl32swap(uint32_t& a, uint32_t& b) {
  typedef int v2i __attribute__((ext_vector_type(2)));
  v2i r = __builtin_amdgcn_permlane32_swap((int)a, (int)b, false, false);
  a = (uint32_t)r.x; b = (uint32_t)r.y;
}
__device__ __forceinline__ uint32_t cvtpk(float lo, float hi) {
  uint32_t d;
  asm("v_cvt_pk_bf16_f32 %0, %1, %2" : "=v"(d) : "v"(lo), "v"(hi));
  return d;
}

// ---------------- prep: f32 -> bf16, weight transposes ----------------------
__global__ void prep_kernel(const float* __restrict__ x, const float* __restrict__ Wq,
                            const float* __restrict__ Wk, const float* __restrict__ Wv,
                            const float* __restrict__ Wfc,
                            u16* __restrict__ xb, u16* __restrict__ wt, u16* __restrict__ wfct) {
  const int total = NM*NC + NQKV*NC + NC*NHC;
  for (int i = blockIdx.x*blockDim.x + threadIdx.x; i < total; i += gridDim.x*blockDim.x) {
    if (i < NM*NC) {
      xb[i] = f2b(x[i]);
    } else if (i < NM*NC + NQKV*NC) {
      int j = i - NM*NC;              // j = n*256 + c ; n = proj*2048 + h*256 + d
      int n = j >> 8, c = j & 255;
      int proj = n >> 11, h = (n >> 8) & 7, d = n & 255;
      const float* W = (proj == 0) ? Wq : (proj == 1) ? Wk : Wv;
      wt[j] = f2b(W[((size_t)(h*NC + c))*NC + d]);     // wt[n][c] = W[h][c][d]
    } else {
      int j = i - NM*NC - NQKV*NC;    // j = d*2048 + jj
      int d = j >> 11, jj = j & 2047;
      wfct[j] = f2b(Wfc[(size_t)jj*NC + d]);           // wfct[d][jj] = Wfc[jj][d]
    }
  }
}

// ---------------- fused QKV projection GEMM (head-group aware) --------------
// Q/K scatter row-major to [b,hloc,s,d]; V scatters TILED-TRANSPOSED to
// [b,hloc][kt=s>>5][256 d][32 s&31]  (16KB contiguous per attn KV-tile).
__global__ void gemm_qkv(const u16* __restrict__ xb, const u16* __restrict__ wt,
                         const float* __restrict__ bq, const float* __restrict__ bk,
                         const float* __restrict__ bv,
                         u16* __restrict__ qo, u16* __restrict__ ko, u16* __restrict__ vo,
                         int h0, int hg, int lg_hg) {
  __shared__ u16 As[128*32];
  __shared__ u16 Bs[128*32];
  const int tid = threadIdx.x;
  const int w = tid >> 6, l = tid & 63;
  const int wr = w >> 1, wc = w & 1;
  const int m0 = blockIdx.x * 128;
  const int n0 = blockIdx.y * 128;             // within group N
  const int proj = n0 >> (8 + lg_hg);          // n0 / (hg*256)
  const int rem  = n0 & ((hg << 8) - 1);
  const int hloc = rem >> 8;
  const int dbase = rem & 255;                 // 0 or 128
  const int wrow0 = proj*2048 + ((h0 + hloc) << 8) + dbase;
  const int arow = tid >> 2;          // 0..63
  const int acol = (tid & 3) * 8;     // elems
  f32x4 acc[4][4] = {};
  for (int k0 = 0; k0 < 256; k0 += 32) {
    __syncthreads();
#pragma unroll
    for (int i = 0; i < 2; i++) {
      gl_lds16(xb + (size_t)(m0 + i*64 + arow)*256 + k0 + acol, (char*)As + i*4096 + w*1024);
      gl_lds16(wt + (size_t)(wrow0 + i*64 + arow)*256 + k0 + acol, (char*)Bs + i*4096 + w*1024);
    }
    __syncthreads();
    bf16x8 af[4], bfr[4];
#pragma unroll
    for (int mt = 0; mt < 4; mt++)
      af[mt] = *(const bf16x8*)&As[(wr*64 + mt*16 + (l&15))*32 + (l>>4)*8];
#pragma unroll
    for (int nt = 0; nt < 4; nt++)
      bfr[nt] = *(const bf16x8*)&Bs[(wc*64 + nt*16 + (l&15))*32 + (l>>4)*8];
#pragma unroll
    for (int mt = 0; mt < 4; mt++)
#pragma unroll
      for (int nt = 0; nt < 4; nt++)
        acc[mt][nt] = __builtin_amdgcn_mfma_f32_16x16x32_bf16(af[mt], bfr[nt], acc[mt][nt], 0, 0, 0);
  }
  if (proj == 2) {
    // V: +bias, ->bf16, tiled-transposed store (8B packed; s base mult of 4)
#pragma unroll
    for (int mt = 0; mt < 4; mt++) {
#pragma unroll
      for (int nt = 0; nt < 4; nt++) {
        const int dd = dbase + wc*64 + nt*16 + (l & 15);
        const float bb_ = bv[((h0 + hloc) << 8) + dd];
        const int m = m0 + wr*64 + mt*16 + ((l>>4)<<2);
        const int b = m >> 11, s = m & 2047;
        u16 pk[4];
#pragma unroll
        for (int j = 0; j < 4; j++) pk[j] = f2b(acc[mt][nt][j] + bb_);
        *(u64*)&vo[(size_t)(b*hg + hloc)*524288 + (size_t)(s>>5)*8192 + dd*32 + (s&31)]
            = *(const u64*)pk;
      }
    }
  } else {
    const float* bias = (proj == 0) ? bq : bk;
    u16* dst = (proj == 0) ? qo : ko;
#pragma unroll
    for (int mt = 0; mt < 4; mt++) {
#pragma unroll
      for (int nt = 0; nt < 4; nt++) {
        const int dd = dbase + wc*64 + nt*16 + (l & 15);
        const float bb_ = bias[((h0 + hloc) << 8) + dd];
#pragma unroll
        for (int j = 0; j < 4; j++) {
          const int m = m0 + wr*64 + mt*16 + ((l>>4)<<2) + j;
          const int b = m >> 11, s = m & 2047;
          dst[((size_t)((b*hg + hloc)*2048 + s))*256 + dd] = f2b(acc[mt][nt][j] + bb_);
        }
      }
    }
  }
}

// ---------------- flash attention: 32x32 MFMA, swapped operands -------------
// Wave = 32 q-rows, block = 128 q. KVBLK=32, double-buffered (r11 structure).
// QK^T: S^T = mfma(K-frag, Q-frag) with 2-WAY SPLIT accumulators (the ONLY
// change vs r11): dependent-MFMA chain 16 -> 8, raw sums folded into p[].
// Softmax: in-lane + permlane32_swap; P via cvt_pk (no LDS round-trip).
// PV: O^T = mfma(V^T-frag, P-frag).
// Ks[2][32][256]: granule^row; Vts[2][256][32]: granule^((d>>1)&3).
__global__ void __launch_bounds__(256, 2)
attn_kernel(const u16* __restrict__ q, const u16* __restrict__ k,
            const u16* __restrict__ vt, u16* __restrict__ cat,
            int h0, int hg, int lg_hg) {
  __shared__ u16 Ks[2][32*256];
  __shared__ u16 Vts[2][256*32];
  const int tid = threadIdx.x;
  const int w = tid >> 6, l = tid & 63;
  const int q31 = l & 31, hh = l >> 5;
  const int bh = blockIdx.y;                   // b*hg + hloc
  const int b = bh >> lg_hg, hloc = bh & (hg - 1);
  const int q0 = blockIdx.x * 128;
  const u16* qp  = q  + (size_t)bh * NS * 256;
  const u16* kp  = k  + (size_t)bh * NS * 256;
  const u16* vtp = vt + (size_t)bh * 524288;

  // Q B-frags: lane supplies Q[q=q31][d = ks*16 + hh*8 + e]
  bf16x8 qf[16];
  {
    const u16* qr = qp + (size_t)(q0 + w*32 + q31)*256 + hh*8;
#pragma unroll
    for (int ks = 0; ks < 16; ks++) qf[ks] = *(const bf16x8*)(qr + ks*16);
  }
  f32x16 o[8];
#pragma unroll
  for (int i = 0; i < 8; i++)
#pragma unroll
    for (int j = 0; j < 16; j++) o[i][j] = 0.f;
  float mrow = -1e30f, lsum = 0.f;
  const float sc = 0.0625f * 1.4426950408889634f;   // 1/sqrt(256) * log2(e)

  // stage KVBLK=32 tile (K 16KB + V^T 16KB) into buffer buf
  auto stage = [&](int buf, int kt) {
#pragma unroll
    for (int i = 0; i < 4; i++) {
      const int g = (w*4 + i)*64 + l;          // granule 0..1023
      const int krow = g >> 5, kcol = g & 31;
      gl_lds16(kp + (size_t)(kt*32 + krow)*256 + ((kcol ^ krow) << 3),
               (char*)&Ks[buf][0] + (w*4 + i)*1024);
      const int vd = g >> 2, vcol = g & 3;
      gl_lds16(vtp + (size_t)kt*8192 + vd*32 + ((vcol ^ ((vd >> 1) & 3)) << 3),
               (char*)&Vts[buf][0] + (w*4 + i)*1024);
    }
  };

  stage(0, 0);
  __syncthreads();

  for (int kt = 0; kt < NS/32; kt++) {
    const int buf = kt & 1;
    if (kt + 1 < NS/32) stage(buf ^ 1, kt + 1);   // flies under compute

    // QK^T swapped, 2-way split accumulators (dep chain 16 -> 8)
    f32x16 sa0, sa1;
#pragma unroll
    for (int i = 0; i < 16; i++) { sa0[i] = 0.f; sa1[i] = 0.f; }
    __builtin_amdgcn_s_setprio(1);
#pragma unroll
    for (int j = 0; j < 8; j++) {
      const bf16x8 kf0 = *(const bf16x8*)&Ks[buf][q31*256 + (((4*j + hh) ^ q31) << 3)];
      sa0 = __builtin_amdgcn_mfma_f32_32x32x16_bf16(kf0, qf[2*j], sa0, 0, 0, 0);
      const bf16x8 kf1 = *(const bf16x8*)&Ks[buf][q31*256 + (((4*j + 2 + hh) ^ q31) << 3)];
      sa1 = __builtin_amdgcn_mfma_f32_32x32x16_bf16(kf1, qf[2*j + 1], sa1, 0, 0, 0);
    }
    __builtin_amdgcn_s_setprio(0);

    // fold raw sums into p[] (no extra live vector beyond sa1)
    float p[16];
#pragma unroll
    for (int r = 0; r < 16; r++) p[r] = sa0[r] + sa1[r];

    // softmax over kv (16 in-lane + partner via permlane32_swap), defer-max
    float m0 = fmaxf(fmaxf(p[0], p[1]),   fmaxf(p[2], p[3]));
    float m1 = fmaxf(fmaxf(p[4], p[5]),   fmaxf(p[6], p[7]));
    float m2 = fmaxf(fmaxf(p[8], p[9]),   fmaxf(p[10], p[11]));
    float m3 = fmaxf(fmaxf(p[12], p[13]), fmaxf(p[14], p[15]));
    float mo = fmaxf(fmaxf(m0, m1), fmaxf(m2, m3));
    uint32_t ma = __builtin_bit_cast(uint32_t, mo), mb = ma;
    pl32swap(ma, mb);
    const float pm = fmaxf(__builtin_bit_cast(float, ma),
                           __builtin_bit_cast(float, mb)) * sc;
    const bool upd = !__all(pm - mrow <= 8.0f);
    if (upd) {
      const float mn = fmaxf(mrow, pm);
      const float fr = exp2f(mrow - mn);
      mrow = mn; lsum *= fr;
#pragma unroll
      for (int i = 0; i < 8; i++) o[i] *= fr;
    }
#pragma unroll
    for (int r = 0; r < 16; r++) p[r] = exp2f(p[r]*sc - mrow);
    float s0 = (p[0] + p[1]) + (p[2] + p[3]);
    float s1 = (p[4] + p[5]) + (p[6] + p[7]);
    float s2 = (p[8] + p[9]) + (p[10] + p[11]);
    float s3 = (p[12] + p[13]) + (p[14] + p[15]);
    float ps = (s0 + s1) + (s2 + s3);
    uint32_t sa_ = __builtin_bit_cast(uint32_t, ps), sb_ = sa_;
    pl32swap(sa_, sb_);
    lsum += __builtin_bit_cast(float, sa_) + __builtin_bit_cast(float, sb_);

    // P -> bf16 B-frags entirely in registers (T12)
    uint32_t wv[8];
#pragma unroll
    for (int i = 0; i < 8; i++) wv[i] = cvtpk(p[2*i], p[2*i + 1]);
    pl32swap(wv[0], wv[2]); pl32swap(wv[1], wv[3]);
    pl32swap(wv[4], wv[6]); pl32swap(wv[5], wv[7]);
    uint4 u0; u0.x = wv[0]; u0.y = wv[1]; u0.z = wv[2]; u0.w = wv[3];
    uint4 u1; u1.x = wv[4]; u1.y = wv[5]; u1.z = wv[6]; u1.w = wv[7];
    const bf16x8 pb0 = __builtin_bit_cast(bf16x8, u0);
    const bf16x8 pb1 = __builtin_bit_cast(bf16x8, u1);

    // PV swapped: o[d][q] += mfma(V^T-frag, P-frag)
    __builtin_amdgcn_s_setprio(1);
#pragma unroll
    for (int dt = 0; dt < 8; dt++) {
      const int drow = dt*32 + q31;
      const int swz = (drow >> 1) & 3;
      const bf16x8 vf0 = *(const bf16x8*)&Vts[buf][drow*32 + ((hh ^ swz) << 3)];
      o[dt] = __builtin_amdgcn_mfma_f32_32x32x16_bf16(vf0, pb0, o[dt], 0, 0, 0);
      const bf16x8 vf1 = *(const bf16x8*)&Vts[buf][drow*32 + (((2 + hh) ^ swz) << 3)];
      o[dt] = __builtin_amdgcn_mfma_f32_32x32x16_bf16(vf1, pb1, o[dt], 0, 0, 0);
    }
    __builtin_amdgcn_s_setprio(0);

    __syncthreads();   // drains vmcnt (stage kt+1 landed) + buffer protection
  }

  // epilogue: o rows d = dt*32 + (r&3) + 8*(r>>2) + 4*hh, col q = q31
  const int hd = h0 + hloc;
  const float inv = 1.f / lsum;
  u16* crow = cat + ((size_t)(b*NS + (q0 + w*32 + q31))*8 + hd)*256 + 4*hh;
#pragma unroll
  for (int dt = 0; dt < 8; dt++) {
#pragma unroll
    for (int m = 0; m < 4; m++) {
      u16 pk4[4];
#pragma unroll
      for (int j = 0; j < 4; j++) pk4[j] = f2b(o[dt][4*m + j] * inv);
      *(u64*)&crow[dt*32 + 8*m] = *(const u64*)pk4;
    }
  }
}

// ---------------- FC GEMM + bias + residual (writes f32 to d_out) -----------
__global__ void gemm_fc(const u16* __restrict__ cat, const u16* __restrict__ wfct,
                        const float* __restrict__ bfc, const float* __restrict__ x,
                        float* __restrict__ fcb) {
  __shared__ u16 As[128*32];
  __shared__ u16 Bs[64*32];
  const int tid = threadIdx.x;
  const int w = tid >> 6, l = tid & 63;
  const int wr = w >> 1, wc = w & 1;
  const int m0 = blockIdx.x * 128;
  const int n0 = blockIdx.y * 64;
  const int arow = tid >> 2;
  const int acol = (tid & 3) * 8;
  f32x4 acc[4][2] = {};
  for (int k0 = 0; k0 < 2048; k0 += 32) {
    __syncthreads();
#pragma unroll
    for (int i = 0; i < 2; i++)
      gl_lds16(cat + (size_t)(m0 + i*64 + arow)*2048 + k0 + acol, (char*)As + i*4096 + w*1024);
    gl_lds16(wfct + (size_t)(n0 + arow)*2048 + k0 + acol, (char*)Bs + w*1024);
    __syncthreads();
    bf16x8 af[4], bfr[2];
#pragma unroll
    for (int mt = 0; mt < 4; mt++)
      af[mt] = *(const bf16x8*)&As[(wr*64 + mt*16 + (l&15))*32 + (l>>4)*8];
#pragma unroll
    for (int nt = 0; nt < 2; nt++)
      bfr[nt] = *(const bf16x8*)&Bs[(wc*32 + nt*16 + (l&15))*32 + (l>>4)*8];
#pragma unroll
    for (int mt = 0; mt < 4; mt++)
#pragma unroll
      for (int nt = 0; nt < 2; nt++)
        acc[mt][nt] = __builtin_amdgcn_mfma_f32_16x16x32_bf16(af[mt], bfr[nt], acc[mt][nt], 0, 0, 0);
  }
#pragma unroll
  for (int mt = 0; mt < 4; mt++) {
#pragma unroll
    for (int nt = 0; nt < 2; nt++) {
      const int n = n0 + wc*32 + nt*16 + (l & 15);
      const float bias = bfc[n];
#pragma unroll
      for (int j = 0; j < 4; j++) {
        const int m = m0 + wr*64 + mt*16 + ((l>>4)<<2) + j;
        fcb[(size_t)m*256 + n] = acc[mt][nt][j] + bias + x[(size_t)m*256 + n];
      }
    }
  }
}

// ---------------- LayerNorm (in-place on d_out) -----------------------------
__global__ void ln_kernel(const float* __restrict__ fcb, const float* __restrict__ gamma,
                          const float* __restrict__ beta, float* __restrict__ out) {
  const int row = blockIdx.x * 4 + (threadIdx.x >> 6);
  const int l = threadIdx.x & 63;
  const float* r = fcb + (size_t)row * 256;
  f32x4 vv = *(const f32x4*)(r + l*4);
  float s  = vv[0] + vv[1] + vv[2] + vv[3];
  float s2 = vv[0]*vv[0] + vv[1]*vv[1] + vv[2]*vv[2] + vv[3]*vv[3];
#pragma unroll
  for (int mof = 1; mof <= 32; mof <<= 1) {
    s  += __shfl_xor(s, mof);
    s2 += __shfl_xor(s2, mof);
  }
  const float mu = s * (1.f/256.f);
  const float var = s2 * (1.f/256.f) - mu*mu;
  const float rs = rsqrtf(var + 1e-5f);
  f32x4 ov;
#pragma unroll
  for (int j = 0; j < 4; j++)
    ov[j] = (vv[j] - mu) * rs * gamma[l*4 + j] + beta[l*4 + j];
  *(f32x4*)(out + (size_t)row*256 + l*4) = ov;
}

// ---------------- launch ----------------------------------------------------
extern "C" void kernel_launch(void* const* d_in, const int* in_sizes, int n_in,
                              void* d_out, int out_size, void* d_ws, size_t ws_size,
                              hipStream_t stream) {
  (void)in_sizes; (void)n_in; (void)out_size;
  const float* x     = (const float*)d_in[0];
  const float* Wq    = (const float*)d_in[1];
  const float* bq    = (const float*)d_in[2];
  const float* Wk    = (const float*)d_in[3];
  const float* bk    = (const float*)d_in[4];
  const float* Wv    = (const float*)d_in[5];
  const float* bv    = (const float*)d_in[6];
  const float* Wfc   = (const float*)d_in[7];
  const float* bfc   = (const float*)d_in[8];
  const float* gamma = (const float*)d_in[9];
  const float* beta  = (const float*)d_in[10];
  float* out = (float*)d_out;

  // Head-group size chosen from ws_size (deterministic). Footprint 40+12*hg MiB.
  int hg, lg_hg;
  if      (ws_size >= (136ull << 20)) { hg = 8; lg_hg = 3; }
  else if (ws_size >= (88ull  << 20)) { hg = 4; lg_hg = 2; }
  else if (ws_size >= (64ull  << 20)) { hg = 2; lg_hg = 1; }
  else                                { hg = 1; lg_hg = 0; }

  char* ws = (char*)d_ws;
  u16*   xb   = (u16*)(ws);                               //  4 MiB x bf16 [8192][256]
  u16*   wt   = (u16*)(ws + (4ull<<20));                  //  3 MiB Wqkv^T bf16 [6144][256]
  u16*   wfct = (u16*)(ws + (7ull<<20));                  //  1 MiB Wfc^T bf16 [256][2048]
  const size_t grp = (size_t)hg << 22;                    //  4*hg MiB per q/k/v buffer
  u16*   qb   = (u16*)(ws + (8ull<<20));
  u16*   kb   = (u16*)(ws + (8ull<<20) + grp);
  u16*   vb   = (u16*)(ws + (8ull<<20) + 2*grp);          // V tiled-transposed (32-tiles)
  u16*   catb = (u16*)(ws + (8ull<<20) + 3*grp);          // 32 MiB cat bf16 [8192][2048]

  prep_kernel<<<dim3(1024), dim3(256), 0, stream>>>(x, Wq, Wk, Wv, Wfc, xb, wt, wfct);
  for (int g = 0; g < NH / hg; g++) {
    const int h0 = g * hg;
    gemm_qkv<<<dim3(64, 6*hg), dim3(256), 0, stream>>>(xb, wt, bq, bk, bv, qb, kb, vb, h0, hg, lg_hg);
    attn_kernel<<<dim3(16, 4*hg), dim3(256), 0, stream>>>(qb, kb, vb, catb, h0, hg, lg_hg);
  }
  gemm_fc<<<dim3(64, 4), dim3(256), 0, stream>>>(catb, wfct, bfc, x, out);
  ln_kernel<<<dim3(2048), dim3(256), 0, stream>>>(out, gamma, beta, out);
}

// Round 15
// 277.476 us; speedup vs baseline: 2.2736x; 1.0744x over previous
//
#include <hip/hip_runtime.h>
#include <stdint.h>

typedef unsigned short u16;
typedef unsigned long long u64;
typedef __bf16 bf16x8 __attribute__((ext_vector_type(8)));
typedef float f32x4 __attribute__((ext_vector_type(4)));
typedef float f32x16 __attribute__((ext_vector_type(16)));

#define NB 4
#define NS 2048
#define NC 256
#define NH 8
#define NM (NB*NS)        // 8192 rows (b,s)
#define NQKV (3*NH*NC)    // 6144
#define NHC (NH*NC)       // 2048

__device__ __forceinline__ u16 f2b(float f) {
  uint32_t u = __builtin_bit_cast(uint32_t, f);
  u += 0x7FFFu + ((u >> 16) & 1u);   // RNE
  return (u16)(u >> 16);
}
__device__ __forceinline__ void gl_lds16(const void* g, void* s) {
  __builtin_amdgcn_global_load_lds((const __attribute__((address_space(1))) void*)g,
                                   (__attribute__((address_space(3))) void*)s, 16, 0, 0);
}
// v_permlane32_swap_b32: a' = {lanes<32: a, lanes>=32: b[l-32]};
//                        b' = {lanes<32: a[l+32], lanes>=32: b}
__device__ __forceinline__ void pl32swap(uint32_t& a, uint32_t& b) {
  typedef int v2i __attribute__((ext_vector_type(2)));
  v2i r = __builtin_amdgcn_permlane32_swap((int)a, (int)b, false, false);
  a = (uint32_t)r.x; b = (uint32_t)r.y;
}
__device__ __forceinline__ uint32_t cvtpk(float lo, float hi) {
  uint32_t d;
  asm("v_cvt_pk_bf16_f32 %0, %1, %2" : "=v"(d) : "v"(lo), "v"(hi));
  return d;
}

// ---------------- prep: f32 -> bf16, weight transposes ----------------------
__global__ void prep_kernel(const float* __restrict__ x, const float* __restrict__ Wq,
                            const float* __restrict__ Wk, const float* __restrict__ Wv,
                            const float* __restrict__ Wfc,
                            u16* __restrict__ xb, u16* __restrict__ wt, u16* __restrict__ wfct) {
  const int total = NM*NC + NQKV*NC + NC*NHC;
  for (int i = blockIdx.x*blockDim.x + threadIdx.x; i < total; i += gridDim.x*blockDim.x) {
    if (i < NM*NC) {
      xb[i] = f2b(x[i]);
    } else if (i < NM*NC + NQKV*NC) {
      int j = i - NM*NC;              // j = n*256 + c ; n = proj*2048 + h*256 + d
      int n = j >> 8, c = j & 255;
      int proj = n >> 11, h = (n >> 8) & 7, d = n & 255;
      const float* W = (proj == 0) ? Wq : (proj == 1) ? Wk : Wv;
      wt[j] = f2b(W[((size_t)(h*NC + c))*NC + d]);     // wt[n][c] = W[h][c][d]
    } else {
      int j = i - NM*NC - NQKV*NC;    // j = d*2048 + jj
      int d = j >> 11, jj = j & 2047;
      wfct[j] = f2b(Wfc[(size_t)jj*NC + d]);           // wfct[d][jj] = Wfc[jj][d]
    }
  }
}

// ---------------- fused QKV projection GEMM (head-group aware) --------------
// Q/K scatter row-major to [b,hloc,s,d]; V scatters TILED-TRANSPOSED to
// [b,hloc][kt=s>>5][256 d][32 s&31]  (16KB contiguous per attn KV-tile).
__global__ void gemm_qkv(const u16* __restrict__ xb, const u16* __restrict__ wt,
                         const float* __restrict__ bq, const float* __restrict__ bk,
                         const float* __restrict__ bv,
                         u16* __restrict__ qo, u16* __restrict__ ko, u16* __restrict__ vo,
                         int h0, int hg, int lg_hg) {
  __shared__ u16 As[128*32];
  __shared__ u16 Bs[128*32];
  const int tid = threadIdx.x;
  const int w = tid >> 6, l = tid & 63;
  const int wr = w >> 1, wc = w & 1;
  const int m0 = blockIdx.x * 128;
  const int n0 = blockIdx.y * 128;             // within group N
  const int proj = n0 >> (8 + lg_hg);          // n0 / (hg*256)
  const int rem  = n0 & ((hg << 8) - 1);
  const int hloc = rem >> 8;
  const int dbase = rem & 255;                 // 0 or 128
  const int wrow0 = proj*2048 + ((h0 + hloc) << 8) + dbase;
  const int arow = tid >> 2;          // 0..63
  const int acol = (tid & 3) * 8;     // elems
  f32x4 acc[4][4] = {};
  for (int k0 = 0; k0 < 256; k0 += 32) {
    __syncthreads();
#pragma unroll
    for (int i = 0; i < 2; i++) {
      gl_lds16(xb + (size_t)(m0 + i*64 + arow)*256 + k0 + acol, (char*)As + i*4096 + w*1024);
      gl_lds16(wt + (size_t)(wrow0 + i*64 + arow)*256 + k0 + acol, (char*)Bs + i*4096 + w*1024);
    }
    __syncthreads();
    bf16x8 af[4], bfr[4];
#pragma unroll
    for (int mt = 0; mt < 4; mt++)
      af[mt] = *(const bf16x8*)&As[(wr*64 + mt*16 + (l&15))*32 + (l>>4)*8];
#pragma unroll
    for (int nt = 0; nt < 4; nt++)
      bfr[nt] = *(const bf16x8*)&Bs[(wc*64 + nt*16 + (l&15))*32 + (l>>4)*8];
#pragma unroll
    for (int mt = 0; mt < 4; mt++)
#pragma unroll
      for (int nt = 0; nt < 4; nt++)
        acc[mt][nt] = __builtin_amdgcn_mfma_f32_16x16x32_bf16(af[mt], bfr[nt], acc[mt][nt], 0, 0, 0);
  }
  if (proj == 2) {
    // V: +bias, ->bf16, tiled-transposed store (8B packed; s base mult of 4)
#pragma unroll
    for (int mt = 0; mt < 4; mt++) {
#pragma unroll
      for (int nt = 0; nt < 4; nt++) {
        const int dd = dbase + wc*64 + nt*16 + (l & 15);
        const float bb_ = bv[((h0 + hloc) << 8) + dd];
        const int m = m0 + wr*64 + mt*16 + ((l>>4)<<2);
        const int b = m >> 11, s = m & 2047;
        u16 pk[4];
#pragma unroll
        for (int j = 0; j < 4; j++) pk[j] = f2b(acc[mt][nt][j] + bb_);
        *(u64*)&vo[(size_t)(b*hg + hloc)*524288 + (size_t)(s>>5)*8192 + dd*32 + (s&31)]
            = *(const u64*)pk;
      }
    }
  } else {
    const float* bias = (proj == 0) ? bq : bk;
    u16* dst = (proj == 0) ? qo : ko;
#pragma unroll
    for (int mt = 0; mt < 4; mt++) {
#pragma unroll
      for (int nt = 0; nt < 4; nt++) {
        const int dd = dbase + wc*64 + nt*16 + (l & 15);
        const float bb_ = bias[((h0 + hloc) << 8) + dd];
#pragma unroll
        for (int j = 0; j < 4; j++) {
          const int m = m0 + wr*64 + mt*16 + ((l>>4)<<2) + j;
          const int b = m >> 11, s = m & 2047;
          dst[((size_t)((b*hg + hloc)*2048 + s))*256 + dd] = f2b(acc[mt][nt][j] + bb_);
        }
      }
    }
  }
}

// ---------------- flash attention: 32x32 MFMA, swapped operands -------------
// Wave = 32 q-rows (one 32x32 tile), block = 128 q. KVBLK=32, double-buffered.
// QK^T: S^T = mfma(K-frag, Q-frag) -> lane holds S[16 kv-rows][q=lane&31].
// Softmax: in-lane reduce + permlane32_swap (no LDS, no 16-lane shuffles).
// P: cvt_pk_bf16 + permlane32_swap -> PV B-frag in registers (no Ps LDS).
// PV: O^T = mfma(V^T-frag, P-frag) -> o[d][q].
// Ks[2][32][256]: granule^row; Vts[2][256][32]: granule^((d>>1)&3) —
// (d>>1) decorrelates bank-quad from row parity within each 16-lane quarter.
__global__ void __launch_bounds__(256, 2)
attn_kernel(const u16* __restrict__ q, const u16* __restrict__ k,
            const u16* __restrict__ vt, u16* __restrict__ cat,
            int h0, int hg, int lg_hg) {
  __shared__ u16 Ks[2][32*256];
  __shared__ u16 Vts[2][256*32];
  const int tid = threadIdx.x;
  const int w = tid >> 6, l = tid & 63;
  const int q31 = l & 31, hh = l >> 5;
  const int bh = blockIdx.y;                   // b*hg + hloc
  const int b = bh >> lg_hg, hloc = bh & (hg - 1);
  const int q0 = blockIdx.x * 128;
  const u16* qp  = q  + (size_t)bh * NS * 256;
  const u16* kp  = k  + (size_t)bh * NS * 256;
  const u16* vtp = vt + (size_t)bh * 524288;

  // Q B-frags: lane supplies Q[q=q31][d = ks*16 + hh*8 + e]
  bf16x8 qf[16];
  {
    const u16* qr = qp + (size_t)(q0 + w*32 + q31)*256 + hh*8;
#pragma unroll
    for (int ks = 0; ks < 16; ks++) qf[ks] = *(const bf16x8*)(qr + ks*16);
  }
  f32x16 o[8];
#pragma unroll
  for (int i = 0; i < 8; i++)
#pragma unroll
    for (int j = 0; j < 16; j++) o[i][j] = 0.f;
  float mrow = -1e30f, lsum = 0.f;
  const float sc = 0.0625f * 1.4426950408889634f;   // 1/sqrt(256) * log2(e)

  // stage KVBLK=32 tile (K 16KB + V^T 16KB) into buffer buf
  auto stage = [&](int buf, int kt) {
#pragma unroll
    for (int i = 0; i < 4; i++) {
      const int g = (w*4 + i)*64 + l;          // granule 0..1023
      const int krow = g >> 5, kcol = g & 31;
      gl_lds16(kp + (size_t)(kt*32 + krow)*256 + ((kcol ^ krow) << 3),
               (char*)&Ks[buf][0] + (w*4 + i)*1024);
      const int vd = g >> 2, vcol = g & 3;
      gl_lds16(vtp + (size_t)kt*8192 + vd*32 + ((vcol ^ ((vd >> 1) & 3)) << 3),
               (char*)&Vts[buf][0] + (w*4 + i)*1024);
    }
  };

  stage(0, 0);
  __syncthreads();

  for (int kt = 0; kt < NS/32; kt++) {
    const int buf = kt & 1;
    if (kt + 1 < NS/32) stage(buf ^ 1, kt + 1);   // flies under compute

    // QK^T swapped: sacc = S^T[kv][q]: A = K-frag (LDS), B = Q (regs)
    f32x16 sacc;
#pragma unroll
    for (int i = 0; i < 16; i++) sacc[i] = 0.f;
    __builtin_amdgcn_s_setprio(1);
#pragma unroll
    for (int ks = 0; ks < 16; ks++) {
      const bf16x8 kf = *(const bf16x8*)&Ks[buf][q31*256 + (((2*ks + hh) ^ q31) << 3)];
      sacc = __builtin_amdgcn_mfma_f32_32x32x16_bf16(kf, qf[ks], sacc, 0, 0, 0);
    }
    __builtin_amdgcn_s_setprio(0);

    // softmax over kv (16 in-lane + partner via permlane32_swap), defer-max
    float m0 = fmaxf(fmaxf(sacc[0], sacc[1]),   fmaxf(sacc[2], sacc[3]));
    float m1 = fmaxf(fmaxf(sacc[4], sacc[5]),   fmaxf(sacc[6], sacc[7]));
    float m2 = fmaxf(fmaxf(sacc[8], sacc[9]),   fmaxf(sacc[10], sacc[11]));
    float m3 = fmaxf(fmaxf(sacc[12], sacc[13]), fmaxf(sacc[14], sacc[15]));
    float mo = fmaxf(fmaxf(m0, m1), fmaxf(m2, m3));
    uint32_t ma = __builtin_bit_cast(uint32_t, mo), mb = ma;
    pl32swap(ma, mb);
    const float pm = fmaxf(__builtin_bit_cast(float, ma),
                           __builtin_bit_cast(float, mb)) * sc;
    const bool upd = !__all(pm - mrow <= 8.0f);
    if (upd) {
      const float mn = fmaxf(mrow, pm);
      const float fr = exp2f(mrow - mn);
      mrow = mn; lsum *= fr;
#pragma unroll
      for (int i = 0; i < 8; i++) o[i] *= fr;
    }
    float p[16];
#pragma unroll
    for (int r = 0; r < 16; r++) p[r] = exp2f(sacc[r]*sc - mrow);
    float s0 = (p[0] + p[1]) + (p[2] + p[3]);
    float s1 = (p[4] + p[5]) + (p[6] + p[7]);
    float s2 = (p[8] + p[9]) + (p[10] + p[11]);
    float s3 = (p[12] + p[13]) + (p[14] + p[15]);
    float ps = (s0 + s1) + (s2 + s3);
    uint32_t sa = __builtin_bit_cast(uint32_t, ps), sb = sa;
    pl32swap(sa, sb);
    lsum += __builtin_bit_cast(float, sa) + __builtin_bit_cast(float, sb);

    // P -> bf16 B-frags entirely in registers (T12)
    uint32_t wv[8];
#pragma unroll
    for (int i = 0; i < 8; i++) wv[i] = cvtpk(p[2*i], p[2*i + 1]);
    pl32swap(wv[0], wv[2]); pl32swap(wv[1], wv[3]);
    pl32swap(wv[4], wv[6]); pl32swap(wv[5], wv[7]);
    uint4 u0; u0.x = wv[0]; u0.y = wv[1]; u0.z = wv[2]; u0.w = wv[3];
    uint4 u1; u1.x = wv[4]; u1.y = wv[5]; u1.z = wv[6]; u1.w = wv[7];
    const bf16x8 pb0 = __builtin_bit_cast(bf16x8, u0);
    const bf16x8 pb1 = __builtin_bit_cast(bf16x8, u1);

    // PV swapped: o[d][q] += mfma(V^T-frag, P-frag)
    __builtin_amdgcn_s_setprio(1);
#pragma unroll
    for (int dt = 0; dt < 8; dt++) {
      const int drow = dt*32 + q31;
      const int swz = (drow >> 1) & 3;
      const bf16x8 vf0 = *(const bf16x8*)&Vts[buf][drow*32 + ((hh ^ swz) << 3)];
      o[dt] = __builtin_amdgcn_mfma_f32_32x32x16_bf16(vf0, pb0, o[dt], 0, 0, 0);
      const bf16x8 vf1 = *(const bf16x8*)&Vts[buf][drow*32 + (((2 + hh) ^ swz) << 3)];
      o[dt] = __builtin_amdgcn_mfma_f32_32x32x16_bf16(vf1, pb1, o[dt], 0, 0, 0);
    }
    __builtin_amdgcn_s_setprio(0);

    __syncthreads();   // drains vmcnt (stage kt+1 landed) + buffer protection
  }

  // epilogue: o rows d = dt*32 + (r&3) + 8*(r>>2) + 4*hh, col q = q31
  const int hd = h0 + hloc;
  const float inv = 1.f / lsum;
  u16* crow = cat + ((size_t)(b*NS + (q0 + w*32 + q31))*8 + hd)*256 + 4*hh;
#pragma unroll
  for (int dt = 0; dt < 8; dt++) {
#pragma unroll
    for (int m = 0; m < 4; m++) {
      u16 pk4[4];
#pragma unroll
      for (int j = 0; j < 4; j++) pk4[j] = f2b(o[dt][4*m + j] * inv);
      *(u64*)&crow[dt*32 + 8*m] = *(const u64*)pk4;
    }
  }
}

// ---------------- FC GEMM + bias + residual (writes f32 to d_out) -----------
__global__ void gemm_fc(const u16* __restrict__ cat, const u16* __restrict__ wfct,
                        const float* __restrict__ bfc, const float* __restrict__ x,
                        float* __restrict__ fcb) {
  __shared__ u16 As[128*32];
  __shared__ u16 Bs[64*32];
  const int tid = threadIdx.x;
  const int w = tid >> 6, l = tid & 63;
  const int wr = w >> 1, wc = w & 1;
  const int m0 = blockIdx.x * 128;
  const int n0 = blockIdx.y * 64;
  const int arow = tid >> 2;
  const int acol = (tid & 3) * 8;
  f32x4 acc[4][2] = {};
  for (int k0 = 0; k0 < 2048; k0 += 32) {
    __syncthreads();
#pragma unroll
    for (int i = 0; i < 2; i++)
      gl_lds16(cat + (size_t)(m0 + i*64 + arow)*2048 + k0 + acol, (char*)As + i*4096 + w*1024);
    gl_lds16(wfct + (size_t)(n0 + arow)*2048 + k0 + acol, (char*)Bs + w*1024);
    __syncthreads();
    bf16x8 af[4], bfr[2];
#pragma unroll
    for (int mt = 0; mt < 4; mt++)
      af[mt] = *(const bf16x8*)&As[(wr*64 + mt*16 + (l&15))*32 + (l>>4)*8];
#pragma unroll
    for (int nt = 0; nt < 2; nt++)
      bfr[nt] = *(const bf16x8*)&Bs[(wc*32 + nt*16 + (l&15))*32 + (l>>4)*8];
#pragma unroll
    for (int mt = 0; mt < 4; mt++)
#pragma unroll
      for (int nt = 0; nt < 2; nt++)
        acc[mt][nt] = __builtin_amdgcn_mfma_f32_16x16x32_bf16(af[mt], bfr[nt], acc[mt][nt], 0, 0, 0);
  }
#pragma unroll
  for (int mt = 0; mt < 4; mt++) {
#pragma unroll
    for (int nt = 0; nt < 2; nt++) {
      const int n = n0 + wc*32 + nt*16 + (l & 15);
      const float bias = bfc[n];
#pragma unroll
      for (int j = 0; j < 4; j++) {
        const int m = m0 + wr*64 + mt*16 + ((l>>4)<<2) + j;
        fcb[(size_t)m*256 + n] = acc[mt][nt][j] + bias + x[(size_t)m*256 + n];
      }
    }
  }
}

// ---------------- LayerNorm (in-place on d_out) -----------------------------
__global__ void ln_kernel(const float* __restrict__ fcb, const float* __restrict__ gamma,
                          const float* __restrict__ beta, float* __restrict__ out) {
  const int row = blockIdx.x * 4 + (threadIdx.x >> 6);
  const int l = threadIdx.x & 63;
  const float* r = fcb + (size_t)row * 256;
  f32x4 vv = *(const f32x4*)(r + l*4);
  float s  = vv[0] + vv[1] + vv[2] + vv[3];
  float s2 = vv[0]*vv[0] + vv[1]*vv[1] + vv[2]*vv[2] + vv[3]*vv[3];
#pragma unroll
  for (int mof = 1; mof <= 32; mof <<= 1) {
    s  += __shfl_xor(s, mof);
    s2 += __shfl_xor(s2, mof);
  }
  const float mu = s * (1.f/256.f);
  const float var = s2 * (1.f/256.f) - mu*mu;
  const float rs = rsqrtf(var + 1e-5f);
  f32x4 ov;
#pragma unroll
  for (int j = 0; j < 4; j++)
    ov[j] = (vv[j] - mu) * rs * gamma[l*4 + j] + beta[l*4 + j];
  *(f32x4*)(out + (size_t)row*256 + l*4) = ov;
}

// ---------------- launch ----------------------------------------------------
extern "C" void kernel_launch(void* const* d_in, const int* in_sizes, int n_in,
                              void* d_out, int out_size, void* d_ws, size_t ws_size,
                              hipStream_t stream) {
  (void)in_sizes; (void)n_in; (void)out_size;
  const float* x     = (const float*)d_in[0];
  const float* Wq    = (const float*)d_in[1];
  const float* bq    = (const float*)d_in[2];
  const float* Wk    = (const float*)d_in[3];
  const float* bk    = (const float*)d_in[4];
  const float* Wv    = (const float*)d_in[5];
  const float* bv    = (const float*)d_in[6];
  const float* Wfc   = (const float*)d_in[7];
  const float* bfc   = (const float*)d_in[8];
  const float* gamma = (const float*)d_in[9];
  const float* beta  = (const float*)d_in[10];
  float* out = (float*)d_out;

  // Head-group size chosen from ws_size (deterministic). Footprint 40+12*hg MiB.
  int hg, lg_hg;
  if      (ws_size >= (136ull << 20)) { hg = 8; lg_hg = 3; }
  else if (ws_size >= (88ull  << 20)) { hg = 4; lg_hg = 2; }
  else if (ws_size >= (64ull  << 20)) { hg = 2; lg_hg = 1; }
  else                                { hg = 1; lg_hg = 0; }

  char* ws = (char*)d_ws;
  u16*   xb   = (u16*)(ws);                               //  4 MiB x bf16 [8192][256]
  u16*   wt   = (u16*)(ws + (4ull<<20));                  //  3 MiB Wqkv^T bf16 [6144][256]
  u16*   wfct = (u16*)(ws + (7ull<<20));                  //  1 MiB Wfc^T bf16 [256][2048]
  const size_t grp = (size_t)hg << 22;                    //  4*hg MiB per q/k/v buffer
  u16*   qb   = (u16*)(ws + (8ull<<20));
  u16*   kb   = (u16*)(ws + (8ull<<20) + grp);
  u16*   vb   = (u16*)(ws + (8ull<<20) + 2*grp);          // V tiled-transposed (32-tiles)
  u16*   catb = (u16*)(ws + (8ull<<20) + 3*grp);          // 32 MiB cat bf16 [8192][2048]

  prep_kernel<<<dim3(1024), dim3(256), 0, stream>>>(x, Wq, Wk, Wv, Wfc, xb, wt, wfct);
  for (int g = 0; g < NH / hg; g++) {
    const int h0 = g * hg;
    gemm_qkv<<<dim3(64, 6*hg), dim3(256), 0, stream>>>(xb, wt, bq, bk, bv, qb, kb, vb, h0, hg, lg_hg);
    attn_kernel<<<dim3(16, 4*hg), dim3(256), 0, stream>>>(qb, kb, vb, catb, h0, hg, lg_hg);
  }
  gemm_fc<<<dim3(64, 4), dim3(256), 0, stream>>>(catb, wfct, bfc, x, out);
  ln_kernel<<<dim3(2048), dim3(256), 0, stream>>>(out, gamma, beta, out);
}